// Round 1
// baseline (1469.482 us; speedup 1.0000x reference)
//
#include <hip/hip_runtime.h>
#include <math.h>

#define B_ 32
#define S_ 256
#define H_ 2048
#define NH_ 16
#define HD_ 128
#define M_ (B_*S_)
#define K_ H_

typedef unsigned short u16;
typedef unsigned int   u32;
typedef __attribute__((ext_vector_type(8))) short  short8;   // 8 bf16 (4 VGPRs) MFMA A/B frag
typedef __attribute__((ext_vector_type(8))) unsigned short ushort8;
typedef __attribute__((ext_vector_type(4))) float  floatx4;  // MFMA C/D frag

typedef __attribute__((address_space(3))) u32 lds_u32;
typedef __attribute__((address_space(1))) const u32 glb_u32;

__device__ __forceinline__ u16 rne_bf16(float f) {
    u32 u = __float_as_uint(f);
    return (u16)((u + 0x7fffu + ((u >> 16) & 1u)) >> 16);
}
__device__ __forceinline__ float bf16_to_f(u16 h) {
    return __uint_as_float(((u32)h) << 16);
}
// async 16B global->LDS; lds addr must be wave-uniform base (+ lane*16 implicit)
__device__ __forceinline__ void gll16(const u16* g, u16* l) {
    __builtin_amdgcn_global_load_lds((glb_u32*)g, (lds_u32*)l, 16, 0, 0);
}

// ---------------------------------------------------------------------------
// fp32 -> (hi, lo) bf16 split.  x = hi + lo + O(2^-17 |x|)
// ---------------------------------------------------------------------------
__global__ __launch_bounds__(256) void split_kernel(const float* __restrict__ x,
    u16* __restrict__ hi, u16* __restrict__ lo, int n4)
{
    int i = blockIdx.x * 256 + threadIdx.x;
    if (i >= n4) return;
    float4 v = ((const float4*)x)[i];
    float vv[4] = {v.x, v.y, v.z, v.w};
    u16 h[4], l[4];
#pragma unroll
    for (int j = 0; j < 4; ++j) {
        h[j] = rne_bf16(vv[j]);
        l[j] = rne_bf16(vv[j] - bf16_to_f(h[j]));
    }
    ((ushort4*)hi)[i] = make_ushort4(h[0], h[1], h[2], h[3]);
    ((ushort4*)lo)[i] = make_ushort4(l[0], l[1], l[2], l[3]);
}

// ---------------------------------------------------------------------------
// C = A @ B^T via 3-pass split-bf16 MFMA (hi*hi + hi*lo + lo*hi), fp32 acc.
// 256x256 tile, BK=32, 512 thr = 8 waves (2Mx4N), wave tile 128x64.
// Phase-interleaved schedule (T3+T4+T5): raw s_barrier, lgkmcnt(0) per phase,
// single vmcnt(0) per K-step (staged loads for t+1 stay in flight across the
// whole step t).  LDS 128 KiB: 4 streams x 2 buffers x 16 KiB, plane-major
// chunks (row,kc) at slot kc*256+row -> conflict-free b128 frag reads and
// gll16-linear staging.  T1: bijective XCD swizzle (grid 256 = 8 XCD x 32).
// mode 0: write bf16 head-major [B,NH,S,HD].  mode 1: fp32 [M,2048].
// ---------------------------------------------------------------------------
__global__ __launch_bounds__(512, 2) void gemm_split256(
    const u16* __restrict__ Ahi, const u16* __restrict__ Alo,
    const u16* __restrict__ Bhi, const u16* __restrict__ Blo,
    void* __restrict__ outv, int mode)
{
    __shared__ u16 sAhi[2][8192], sAlo[2][8192], sBhi[2][8192], sBlo[2][8192];

    const int tid  = threadIdx.x;
    const int lane = tid & 63, w = tid >> 6;
    const int wm   = w >> 2, wn = w & 3;            // wave grid 2 (M) x 4 (N)
    const int r15  = lane & 15, quad = lane >> 4;

    // T1: XCD-aware bijective swizzle. 256 wgs, 8 XCDs -> XCD k owns by in [4k,4k+4)
    const int bid = blockIdx.x;
    const int swz = (bid & 7) * 32 + (bid >> 3);
    const int bx  = swz & 7;                         // N-tile 0..7
    const int by  = swz >> 3;                        // M-tile 0..31

    // staging: thread -> (row = tid&255, chunks c0 and c0+2), c0 = tid>>8
    const int srow = tid & 255;
    const int c0   = tid >> 8;
    const u16* gA0 = Ahi + (size_t)(by*256 + srow) * K_ + c0*8;
    const u16* gA1 = Alo + (size_t)(by*256 + srow) * K_ + c0*8;
    const u16* gB0 = Bhi + (size_t)(bx*256 + srow) * K_ + c0*8;
    const u16* gB1 = Blo + (size_t)(bx*256 + srow) * K_ + c0*8;
    // per-wave LDS segments (u16 units): even half = slots tid, odd = 512+tid
    const int segE = w * 512;
    const int segO = 4096 + w * 512;

    // fragment read bases (u16 index): chunk (row,kc) at slot kc*256+row
    const int aBase = (quad*256 + wm*128 + r15) * 8;
    const int bBase = (quad*256 + wn*64  + r15) * 8;

    const floatx4 fzero = {0.f, 0.f, 0.f, 0.f};
    floatx4 acc[8][4];
#pragma unroll
    for (int mi = 0; mi < 8; ++mi)
#pragma unroll
        for (int ni = 0; ni < 4; ++ni) acc[mi][ni] = fzero;

#define STAGE8(nbuf) do {                                                     \
        gll16(gA0,      &sAhi[nbuf][segE]); gll16(gA0 + 16, &sAhi[nbuf][segO]); \
        gll16(gA1,      &sAlo[nbuf][segE]); gll16(gA1 + 16, &sAlo[nbuf][segO]); \
        gll16(gB0,      &sBhi[nbuf][segE]); gll16(gB0 + 16, &sBhi[nbuf][segO]); \
        gll16(gB1,      &sBlo[nbuf][segE]); gll16(gB1 + 16, &sBlo[nbuf][segO]); \
        gA0 += 32; gA1 += 32; gB0 += 32; gB1 += 32; } while (0)

    // prologue: stage K-step 0
    STAGE8(0);
    asm volatile("s_waitcnt vmcnt(0)" ::: "memory");
    __builtin_amdgcn_s_barrier();

    int cur = 0;
    for (int kt = 0; kt < K_/32; ++kt) {
        const int nb = cur ^ 1;
        // issue next K-step's staging first: full step of MFMA cover before the
        // single end-of-step vmcnt(0)
        if (kt < K_/32 - 1) STAGE8(nb);

        // ---- phase A: mi 0..3 x all ni ----
        short8 ah[4], al[4], bh[4], bl[4];
#pragma unroll
        for (int mi = 0; mi < 4; ++mi) {
            ah[mi] = *(const short8*)&sAhi[cur][aBase + mi*128];
            al[mi] = *(const short8*)&sAlo[cur][aBase + mi*128];
        }
#pragma unroll
        for (int ni = 0; ni < 4; ++ni) {
            bh[ni] = *(const short8*)&sBhi[cur][bBase + ni*128];
            bl[ni] = *(const short8*)&sBlo[cur][bBase + ni*128];
        }
        __builtin_amdgcn_s_barrier();
        asm volatile("s_waitcnt lgkmcnt(0)" ::: "memory");
        __builtin_amdgcn_s_setprio(1);
#pragma unroll
        for (int mi = 0; mi < 4; ++mi)
#pragma unroll
            for (int ni = 0; ni < 4; ++ni) {
                acc[mi][ni] = __builtin_amdgcn_mfma_f32_16x16x32_bf16(ah[mi], bh[ni], acc[mi][ni], 0, 0, 0);
                acc[mi][ni] = __builtin_amdgcn_mfma_f32_16x16x32_bf16(ah[mi], bl[ni], acc[mi][ni], 0, 0, 0);
                acc[mi][ni] = __builtin_amdgcn_mfma_f32_16x16x32_bf16(al[mi], bh[ni], acc[mi][ni], 0, 0, 0);
            }
        __builtin_amdgcn_s_setprio(0);
        __builtin_amdgcn_s_barrier();

        // ---- phase B: mi 4..7 x all ni (b-frags still live) ----
        short8 ah2[4], al2[4];
#pragma unroll
        for (int mi = 0; mi < 4; ++mi) {
            ah2[mi] = *(const short8*)&sAhi[cur][aBase + 512 + mi*128];
            al2[mi] = *(const short8*)&sAlo[cur][aBase + 512 + mi*128];
        }
        __builtin_amdgcn_s_barrier();
        asm volatile("s_waitcnt lgkmcnt(0)" ::: "memory");
        __builtin_amdgcn_s_setprio(1);
#pragma unroll
        for (int mi = 0; mi < 4; ++mi)
#pragma unroll
            for (int ni = 0; ni < 4; ++ni) {
                acc[4+mi][ni] = __builtin_amdgcn_mfma_f32_16x16x32_bf16(ah2[mi], bh[ni], acc[4+mi][ni], 0, 0, 0);
                acc[4+mi][ni] = __builtin_amdgcn_mfma_f32_16x16x32_bf16(ah2[mi], bl[ni], acc[4+mi][ni], 0, 0, 0);
                acc[4+mi][ni] = __builtin_amdgcn_mfma_f32_16x16x32_bf16(al2[mi], bh[ni], acc[4+mi][ni], 0, 0, 0);
            }
        __builtin_amdgcn_s_setprio(0);
        // single drain per K-step: buf nb fully landed before next step reads it
        asm volatile("s_waitcnt vmcnt(0)" ::: "memory");
        __builtin_amdgcn_s_barrier();
        cur = nb;
    }
#undef STAGE8

    // C/D layout: col = lane&15, row = quad*4 + reg  [m89/m91 verified]
    if (mode == 0) {
        u16* out = (u16*)outv;                       // [B, NH, S, HD]
#pragma unroll
        for (int mi = 0; mi < 8; ++mi)
#pragma unroll
            for (int r = 0; r < 4; ++r) {
                int m  = by*256 + wm*128 + mi*16 + quad*4 + r;
                int bb = m >> 8, ss = m & 255;
#pragma unroll
                for (int ni = 0; ni < 4; ++ni) {
                    int n = bx*256 + wn*64 + ni*16 + r15;
                    int h = n >> 7, d = n & 127;
                    out[(((size_t)(bb*NH_ + h)) * S_ + ss) * HD_ + d] = rne_bf16(acc[mi][ni][r]);
                }
            }
    } else {
        float* out = (float*)outv;                   // [M, 2048]
#pragma unroll
        for (int mi = 0; mi < 8; ++mi)
#pragma unroll
            for (int r = 0; r < 4; ++r) {
                int m = by*256 + wm*128 + mi*16 + quad*4 + r;
                size_t base = (size_t)m * H_ + bx*256 + wn*64 + r15;
#pragma unroll
                for (int ni = 0; ni < 4; ++ni)
                    out[base + ni*16] = acc[mi][ni][r];
            }
    }
}

// ---------------------------------------------------------------------------
// RoPE in-place on bf16 q,k in [B,NH,S,HD]; pair (i, i+64). Accurate cosf/sinf.
// ---------------------------------------------------------------------------
__global__ __launch_bounds__(256) void rope_bf(u16* __restrict__ q, u16* __restrict__ k)
{
    int idx = blockIdx.x * 256 + threadIdx.x;       // pair index
    u16* p = blockIdx.y ? k : q;
    int i  = idx & 63;
    int s  = (idx >> 6) & (S_ - 1);
    int bh = idx >> 14;
    size_t base = ((size_t)bh * S_ + s) * HD_;
    float f = expf((float)i * -0.14391156831212788f);   // 10000^(-i/64)
    float ang = (float)s * f;
    float c = cosf(ang), sn = sinf(ang);
    float x0 = bf16_to_f(p[base + i]), x1 = bf16_to_f(p[base + i + 64]);
    p[base + i]      = rne_bf16(x0 * c - x1 * sn);
    p[base + i + 64] = rne_bf16(x1 * c + x0 * sn);
}

// ---------------------------------------------------------------------------
// Attention, bf16 MFMA. Block = 256 thr (4 waves) handles (b,h) x 64 q-rows.
// Scores kept in C-layout registers (wave w owns q-rows w*16..+15, all 256 cols);
// softmax via 16-lane shuffle; P -> LDS (plane-major) -> A-operand for PV.
// LDS 48KB: shQK = Qs(16K)+Ks(16K) reused as Pb(32K); shV = Vt transposed (16K).
// Output written as hi/lo split bf16 [M, 2048] for the final split GEMM.
// ---------------------------------------------------------------------------
#define SCALE 0.08838834764831845f

__global__ __launch_bounds__(256) void attn_mfma(
    const u16* __restrict__ Q, const u16* __restrict__ K, const u16* __restrict__ V,
    u16* __restrict__ Ohi, u16* __restrict__ Olo)
{
    __shared__ u16 shQK[16384];
    __shared__ u16 shV[8192];
    u16* Qs = shQK;            // planes [16][64] chunks of 8 bf16
    u16* Ks = shQK + 8192;     // planes [16][64]
    u16* Pb = shQK;            // planes [32][64]  (after Qs/Ks dead)

    const int tid = threadIdx.x;
    const int lane = tid & 63, w = tid >> 6;
    const int r15 = lane & 15, quad = lane >> 4;
    const int bh = blockIdx.x;
    const int q0 = blockIdx.y << 6;
    const int wq = w * 16;

    const u16* Qg = Q + ((size_t)bh * S_ + q0) * HD_;
    const u16* Kg = K + (size_t)bh * S_ * HD_;
    const u16* Vg = V + (size_t)bh * S_ * HD_;

    // stage Q tile 64x128 -> plane-major
#pragma unroll
    for (int p = 0; p < 4; ++p) {
        int task = tid + (p << 8);
        int r = task & 63, c = task >> 6;
        *(uint4*)&Qs[(c*64 + r)*8] = *(const uint4*)&Qg[(size_t)r*HD_ + c*8];
    }

    const floatx4 fzero = {0.f, 0.f, 0.f, 0.f};
    floatx4 sc[4][4];                          // [kt][ni]; rows wq+quad*4+reg
    for (int kt = 0; kt < 4; ++kt) {
        __syncthreads();
#pragma unroll
        for (int p = 0; p < 4; ++p) {
            int task = tid + (p << 8);
            int r = task & 63, c = task >> 6;
            *(uint4*)&Ks[(c*64 + r)*8] = *(const uint4*)&Kg[(size_t)(kt*64 + r)*HD_ + c*8];
        }
        __syncthreads();
#pragma unroll
        for (int ni = 0; ni < 4; ++ni) sc[kt][ni] = fzero;
#pragma unroll
        for (int ks = 0; ks < 4; ++ks) {
            short8 a = *(const short8*)&Qs[((ks*4 + quad)*64 + wq + r15)*8];
#pragma unroll
            for (int ni = 0; ni < 4; ++ni) {
                short8 b = *(const short8*)&Ks[((ks*4 + quad)*64 + ni*16 + r15)*8];
                sc[kt][ni] = __builtin_amdgcn_mfma_f32_16x16x32_bf16(a, b, sc[kt][ni], 0, 0, 0);
            }
        }
    }
    __syncthreads();   // all Qs/Ks reads complete before Pb overwrites them

    // ---- softmax in registers (rows wq+quad*4+r; 16 col-lanes via shuffle) ----
#pragma unroll
    for (int kt = 0; kt < 4; ++kt)
#pragma unroll
        for (int ni = 0; ni < 4; ++ni) sc[kt][ni] *= SCALE;

    float rinv4[4], mrow4[4];
#pragma unroll
    for (int r = 0; r < 4; ++r) {
        float m = -1e30f;
#pragma unroll
        for (int kt = 0; kt < 4; ++kt)
#pragma unroll
            for (int ni = 0; ni < 4; ++ni) m = fmaxf(m, sc[kt][ni][r]);
#pragma unroll
        for (int o = 1; o < 16; o <<= 1) m = fmaxf(m, __shfl_xor(m, o));
        mrow4[r] = m;
    }
#pragma unroll
    for (int r = 0; r < 4; ++r) {
        float ssum = 0.f;
#pragma unroll
        for (int kt = 0; kt < 4; ++kt)
#pragma unroll
            for (int ni = 0; ni < 4; ++ni) {
                float e = __expf(sc[kt][ni][r] - mrow4[r]);
                sc[kt][ni][r] = e;
                ssum += e;
            }
#pragma unroll
        for (int o = 1; o < 16; o <<= 1) ssum += __shfl_xor(ssum, o);
        rinv4[r] = 1.f / ssum;
    }
    // write P bf16 -> Pb plane-major: elem(row,col) at chunk (col>>3)*64+row
#pragma unroll
    for (int r = 0; r < 4; ++r) {
        int row = wq + quad*4 + r;
#pragma unroll
        for (int kt = 0; kt < 4; ++kt)
#pragma unroll
            for (int ni = 0; ni < 4; ++ni) {
                int col = kt*64 + ni*16 + r15;
                Pb[((col >> 3)*64 + row)*8 + (col & 7)] = rne_bf16(sc[kt][ni][r] * rinv4[r]);
            }
    }

    // ---- O = P V ----
    floatx4 oacc[8];
#pragma unroll
    for (int di = 0; di < 8; ++di) oacc[di] = fzero;

    for (int vt = 0; vt < 4; ++vt) {
        __syncthreads();
        // stage V tile transposed: Vt planes [8][128] chunks; elem(d,s') at chunk (s'>>3)*128+d
#pragma unroll
        for (int p = 0; p < 4; ++p) {
            int task = tid + (p << 8);
            int r = task & 63, dc = task >> 6;          // s' = r, d-chunk dc
            ushort8 v = *(const ushort8*)&Vg[(size_t)(vt*64 + r)*HD_ + dc*8];
#pragma unroll
            for (int j = 0; j < 8; ++j)
                shV[(((r >> 3)*128) + dc*8 + j)*8 + (r & 7)] = v[j];
        }
        __syncthreads();
#pragma unroll
        for (int ks = 0; ks < 2; ++ks) {
            int colbase = vt*64 + ks*32 + quad*8;
            short8 a = *(const short8*)&Pb[((colbase >> 3)*64 + wq + r15)*8];
            int sp = ks*32 + quad*8;
#pragma unroll
            for (int di = 0; di < 8; ++di) {
                short8 b = *(const short8*)&shV[((sp >> 3)*128 + di*16 + r15)*8];
                oacc[di] = __builtin_amdgcn_mfma_f32_16x16x32_bf16(a, b, oacc[di], 0, 0, 0);
            }
        }
    }

    // epilogue: att[m][n] -> hi/lo split bf16, m = b*256+s, n = h*128 + d
    const int brow = bh >> 4, h = bh & 15;
#pragma unroll
    for (int r = 0; r < 4; ++r) {
        size_t base = ((size_t)(brow*S_ + q0 + wq + quad*4 + r)) * H_ + h*128 + r15;
#pragma unroll
        for (int di = 0; di < 8; ++di) {
            float x = oacc[di][r];
            u16 hb = rne_bf16(x);
            Ohi[base + di*16] = hb;
            Olo[base + di*16] = rne_bf16(x - bf16_to_f(hb));
        }
    }
}

// ---------------------------------------------------------------------------
extern "C" void kernel_launch(void* const* d_in, const int* in_sizes, int n_in,
                              void* d_out, int out_size, void* d_ws, size_t ws_size,
                              hipStream_t stream)
{
    const float* X  = (const float*)d_in[0];
    const float* Wp[4] = {(const float*)d_in[1], (const float*)d_in[2],
                          (const float*)d_in[3], (const float*)d_in[4]};   // q,k,v,o
    float* outp = (float*)d_out;

    char* ws = (char*)d_ws;
    u16* Xhi = (u16*)ws;                          //  33.5 MB
    u16* Xlo = (u16*)(ws + 33554432);             //  33.5 MB
    u16* Wsp = (u16*)(ws + 67108864);             //  8 x 8.4 MB (hi/lo per W)
    u16* Qbf = (u16*)(ws + 134217728);            //  33.5 MB [B,NH,S,HD]
    u16* Kbf = (u16*)(ws + 167772160);
    u16* Vbf = (u16*)(ws + 201326592);            //  total 235 MB
    u16* Ahi = Xhi;                               // alias: X-split dead after projections
    u16* Alo = Xlo;

    split_kernel<<<(M_*H_/4)/256, 256, 0, stream>>>(X, Xhi, Xlo, M_*H_/4);
    for (int i = 0; i < 4; ++i)
        split_kernel<<<(H_*H_/4)/256, 256, 0, stream>>>(Wp[i],
            Wsp + (size_t)(2*i)*4194304, Wsp + (size_t)(2*i+1)*4194304, H_*H_/4);

    gemm_split256<<<256, 512, 0, stream>>>(Xhi, Xlo, Wsp + 0*4194304, Wsp + 1*4194304, Qbf, 0);
    gemm_split256<<<256, 512, 0, stream>>>(Xhi, Xlo, Wsp + 2*4194304, Wsp + 3*4194304, Kbf, 0);
    gemm_split256<<<256, 512, 0, stream>>>(Xhi, Xlo, Wsp + 4*4194304, Wsp + 5*4194304, Vbf, 0);
    rope_bf<<<dim3(32768, 2), 256, 0, stream>>>(Qbf, Kbf);
    attn_mfma<<<dim3(B_*NH_, 4), 256, 0, stream>>>(Qbf, Kbf, Vbf, Ahi, Alo);
    gemm_split256<<<256, 512, 0, stream>>>(Ahi, Alo, Wsp + 6*4194304, Wsp + 7*4194304, outp, 1);
}

// Round 2
// 1206.535 us; speedup vs baseline: 1.2179x; 1.2179x over previous
//
#include <hip/hip_runtime.h>
#include <math.h>

#define B_ 32
#define S_ 256
#define H_ 2048
#define NH_ 16
#define HD_ 128
#define M_ (B_*S_)
#define K_ H_

typedef unsigned short u16;
typedef unsigned int   u32;
typedef __attribute__((ext_vector_type(8))) short  short8;   // 8 bf16 (4 VGPRs) MFMA A/B frag
typedef __attribute__((ext_vector_type(8))) unsigned short ushort8;
typedef __attribute__((ext_vector_type(4))) float  floatx4;  // MFMA C/D frag

typedef __attribute__((address_space(3))) u32 lds_u32;
typedef __attribute__((address_space(1))) const u32 glb_u32;

__device__ __forceinline__ u16 rne_bf16(float f) {
    u32 u = __float_as_uint(f);
    return (u16)((u + 0x7fffu + ((u >> 16) & 1u)) >> 16);
}
__device__ __forceinline__ float bf16_to_f(u16 h) {
    return __uint_as_float(((u32)h) << 16);
}
// async 16B global->LDS; lds addr must be wave-uniform base (+ lane*16 implicit)
__device__ __forceinline__ void gll16(const u16* g, u16* l) {
    __builtin_amdgcn_global_load_lds((glb_u32*)g, (lds_u32*)l, 16, 0, 0);
}

// ---------------------------------------------------------------------------
// fp32 -> (hi, lo) bf16 split.  x = hi + lo + O(2^-17 |x|)
// ---------------------------------------------------------------------------
__global__ __launch_bounds__(256) void split_kernel(const float* __restrict__ x,
    u16* __restrict__ hi, u16* __restrict__ lo, int n4)
{
    int i = blockIdx.x * 256 + threadIdx.x;
    if (i >= n4) return;
    float4 v = ((const float4*)x)[i];
    float vv[4] = {v.x, v.y, v.z, v.w};
    u16 h[4], l[4];
#pragma unroll
    for (int j = 0; j < 4; ++j) {
        h[j] = rne_bf16(vv[j]);
        l[j] = rne_bf16(vv[j] - bf16_to_f(h[j]));
    }
    ((ushort4*)hi)[i] = make_ushort4(h[0], h[1], h[2], h[3]);
    ((ushort4*)lo)[i] = make_ushort4(l[0], l[1], l[2], l[3]);
}

// ---------------------------------------------------------------------------
// C = A @ B^T via 3-pass split-bf16 MFMA (hi*hi + hi*lo + lo*hi), fp32 acc.
// 256x256 tile, BK=32, 512 thr = 8 waves (2Mx4N), wave tile 128x64.
// Depth-2 counted-vmcnt pipeline (T4): prologue stages tiles 0,1; step t stages
// tile t+2 mid-step (after all reads of buf[cur] drained) and waits only
// vmcnt(8) at step end -> tile t+1 landed, tile t+2 stays in flight.  Never
// drains to 0 in the main loop.  2 barriers/step.  T5 setprio around MFMA.
// LDS 128 KiB: 4 streams x 2 buffers x 16 KiB, plane-major chunks (row,kc) at
// slot kc*256+row -> conflict-free b128 frag reads + gll16-linear staging.
// T1: bijective XCD swizzle (grid 256 = 8 XCD x 32; XCD k owns A-panels 4k..4k+3).
// mode 0: write bf16 head-major [B,NH,S,HD].  mode 1: fp32 [M,2048].
// ---------------------------------------------------------------------------
__global__ __launch_bounds__(512, 2) void gemm_split256(
    const u16* __restrict__ Ahi, const u16* __restrict__ Alo,
    const u16* __restrict__ Bhi, const u16* __restrict__ Blo,
    void* __restrict__ outv, int mode)
{
    __shared__ u16 sAhi[2][8192], sAlo[2][8192], sBhi[2][8192], sBlo[2][8192];

    const int tid  = threadIdx.x;
    const int lane = tid & 63, w = tid >> 6;
    const int wm   = w >> 2, wn = w & 3;            // wave grid 2 (M) x 4 (N)
    const int r15  = lane & 15, quad = lane >> 4;

    // T1: XCD-aware bijective swizzle. 256 wgs, 8 XCDs -> XCD k owns by in [4k,4k+4)
    const int bid = blockIdx.x;
    const int swz = (bid & 7) * 32 + (bid >> 3);
    const int bx  = swz & 7;                         // N-tile 0..7
    const int by  = swz >> 3;                        // M-tile 0..31

    // staging: thread -> (row = tid&255, chunks c0 and c0+2), c0 = tid>>8
    const int srow = tid & 255;
    const int c0   = tid >> 8;
    const u16* gA0 = Ahi + (size_t)(by*256 + srow) * K_ + c0*8;
    const u16* gA1 = Alo + (size_t)(by*256 + srow) * K_ + c0*8;
    const u16* gB0 = Bhi + (size_t)(bx*256 + srow) * K_ + c0*8;
    const u16* gB1 = Blo + (size_t)(bx*256 + srow) * K_ + c0*8;
    // per-wave LDS segments (u16 units): even half = slots tid, odd = 512+tid
    const int segE = w * 512;
    const int segO = 4096 + w * 512;

    // fragment read bases (u16 index): chunk (row,kc) at slot kc*256+row
    const int aBase = (quad*256 + wm*128 + r15) * 8;
    const int bBase = (quad*256 + wn*64  + r15) * 8;

    const floatx4 fzero = {0.f, 0.f, 0.f, 0.f};
    floatx4 acc[8][4];
#pragma unroll
    for (int mi = 0; mi < 8; ++mi)
#pragma unroll
        for (int ni = 0; ni < 4; ++ni) acc[mi][ni] = fzero;

#define STAGE8(nbuf) do {                                                     \
        gll16(gA0,      &sAhi[nbuf][segE]); gll16(gA0 + 16, &sAhi[nbuf][segO]); \
        gll16(gA1,      &sAlo[nbuf][segE]); gll16(gA1 + 16, &sAlo[nbuf][segO]); \
        gll16(gB0,      &sBhi[nbuf][segE]); gll16(gB0 + 16, &sBhi[nbuf][segO]); \
        gll16(gB1,      &sBlo[nbuf][segE]); gll16(gB1 + 16, &sBlo[nbuf][segO]); \
        gA0 += 32; gA1 += 32; gB0 += 32; gB1 += 32; } while (0)

    // prologue: stage tiles 0 and 1; wait only for tile 0 (8 oldest of 16)
    STAGE8(0);
    STAGE8(1);
    asm volatile("s_waitcnt vmcnt(8)" ::: "memory");
    __builtin_amdgcn_s_barrier();

    int cur = 0;
    for (int kt = 0; kt < K_/32; ++kt) {
        // ---- phase A: mi 0..3 x all ni ----
        short8 ah[4], al[4], bh[4], bl[4];
#pragma unroll
        for (int mi = 0; mi < 4; ++mi) {
            ah[mi] = *(const short8*)&sAhi[cur][aBase + mi*128];
            al[mi] = *(const short8*)&sAlo[cur][aBase + mi*128];
        }
#pragma unroll
        for (int ni = 0; ni < 4; ++ni) {
            bh[ni] = *(const short8*)&sBhi[cur][bBase + ni*128];
            bl[ni] = *(const short8*)&sBlo[cur][bBase + ni*128];
        }
        __builtin_amdgcn_s_setprio(1);
#pragma unroll
        for (int mi = 0; mi < 4; ++mi)
#pragma unroll
            for (int ni = 0; ni < 4; ++ni) {
                acc[mi][ni] = __builtin_amdgcn_mfma_f32_16x16x32_bf16(ah[mi], bh[ni], acc[mi][ni], 0, 0, 0);
                acc[mi][ni] = __builtin_amdgcn_mfma_f32_16x16x32_bf16(ah[mi], bl[ni], acc[mi][ni], 0, 0, 0);
                acc[mi][ni] = __builtin_amdgcn_mfma_f32_16x16x32_bf16(al[mi], bh[ni], acc[mi][ni], 0, 0, 0);
            }
        __builtin_amdgcn_s_setprio(0);

        // ---- phase B frag reads (rows +64); then ALL reads of buf[cur] drained ----
        short8 ah2[4], al2[4];
#pragma unroll
        for (int mi = 0; mi < 4; ++mi) {
            ah2[mi] = *(const short8*)&sAhi[cur][aBase + 512 + mi*128];
            al2[mi] = *(const short8*)&sAlo[cur][aBase + 512 + mi*128];
        }
        asm volatile("s_waitcnt lgkmcnt(0)" ::: "memory");
        __builtin_amdgcn_sched_barrier(0);
        __builtin_amdgcn_s_barrier();          // every wave done reading buf[cur]
        __builtin_amdgcn_sched_barrier(0);
        if (kt < K_/32 - 2) {
            STAGE8(cur);                       // tile kt+2 into the just-freed buffer
            __builtin_amdgcn_sched_barrier(0); // pin issue point: no sinking toward the wait
        }

        // ---- phase B MFMA (b-frags still live) ----
        __builtin_amdgcn_s_setprio(1);
#pragma unroll
        for (int mi = 0; mi < 4; ++mi)
#pragma unroll
            for (int ni = 0; ni < 4; ++ni) {
                acc[4+mi][ni] = __builtin_amdgcn_mfma_f32_16x16x32_bf16(ah2[mi], bh[ni], acc[4+mi][ni], 0, 0, 0);
                acc[4+mi][ni] = __builtin_amdgcn_mfma_f32_16x16x32_bf16(ah2[mi], bl[ni], acc[4+mi][ni], 0, 0, 0);
                acc[4+mi][ni] = __builtin_amdgcn_mfma_f32_16x16x32_bf16(al2[mi], bh[ni], acc[4+mi][ni], 0, 0, 0);
            }
        __builtin_amdgcn_s_setprio(0);

        // counted wait: oldest 8 = tile kt+1 (next buffer); tile kt+2 stays in flight
        if (kt < K_/32 - 2)       asm volatile("s_waitcnt vmcnt(8)" ::: "memory");
        else if (kt == K_/32 - 2) asm volatile("s_waitcnt vmcnt(0)" ::: "memory");
        if (kt < K_/32 - 1) __builtin_amdgcn_s_barrier();
        cur ^= 1;
    }
#undef STAGE8

    // C/D layout: col = lane&15, row = quad*4 + reg  [m89/m91 verified]
    if (mode == 0) {
        u16* out = (u16*)outv;                       // [B, NH, S, HD]
#pragma unroll
        for (int mi = 0; mi < 8; ++mi)
#pragma unroll
            for (int r = 0; r < 4; ++r) {
                int m  = by*256 + wm*128 + mi*16 + quad*4 + r;
                int bb = m >> 8, ss = m & 255;
#pragma unroll
                for (int ni = 0; ni < 4; ++ni) {
                    int n = bx*256 + wn*64 + ni*16 + r15;
                    int h = n >> 7, d = n & 127;
                    out[(((size_t)(bb*NH_ + h)) * S_ + ss) * HD_ + d] = rne_bf16(acc[mi][ni][r]);
                }
            }
    } else {
        float* out = (float*)outv;                   // [M, 2048]
#pragma unroll
        for (int mi = 0; mi < 8; ++mi)
#pragma unroll
            for (int r = 0; r < 4; ++r) {
                int m = by*256 + wm*128 + mi*16 + quad*4 + r;
                size_t base = (size_t)m * H_ + bx*256 + wn*64 + r15;
#pragma unroll
                for (int ni = 0; ni < 4; ++ni)
                    out[base + ni*16] = acc[mi][ni][r];
            }
    }
}

// ---------------------------------------------------------------------------
// RoPE in-place on bf16 q,k in [B,NH,S,HD]; pair (i, i+64). Accurate cosf/sinf.
// ---------------------------------------------------------------------------
__global__ __launch_bounds__(256) void rope_bf(u16* __restrict__ q, u16* __restrict__ k)
{
    int idx = blockIdx.x * 256 + threadIdx.x;       // pair index
    u16* p = blockIdx.y ? k : q;
    int i  = idx & 63;
    int s  = (idx >> 6) & (S_ - 1);
    int bh = idx >> 14;
    size_t base = ((size_t)bh * S_ + s) * HD_;
    float f = expf((float)i * -0.14391156831212788f);   // 10000^(-i/64)
    float ang = (float)s * f;
    float c = cosf(ang), sn = sinf(ang);
    float x0 = bf16_to_f(p[base + i]), x1 = bf16_to_f(p[base + i + 64]);
    p[base + i]      = rne_bf16(x0 * c - x1 * sn);
    p[base + i + 64] = rne_bf16(x1 * c + x0 * sn);
}

// ---------------------------------------------------------------------------
// Attention, bf16 MFMA. Block = 256 thr (4 waves) handles (b,h) x 64 q-rows.
// Scores kept in C-layout registers (wave w owns q-rows w*16..+15, all 256 cols);
// softmax via 16-lane shuffle; P -> LDS (plane-major) -> A-operand for PV.
// LDS 48KB: shQK = Qs(16K)+Ks(16K) reused as Pb(32K); shV = Vt transposed (16K).
// Output written as hi/lo split bf16 [M, 2048] for the final split GEMM.
// ---------------------------------------------------------------------------
#define SCALE 0.08838834764831845f

__global__ __launch_bounds__(256) void attn_mfma(
    const u16* __restrict__ Q, const u16* __restrict__ K, const u16* __restrict__ V,
    u16* __restrict__ Ohi, u16* __restrict__ Olo)
{
    __shared__ u16 shQK[16384];
    __shared__ u16 shV[8192];
    u16* Qs = shQK;            // planes [16][64] chunks of 8 bf16
    u16* Ks = shQK + 8192;     // planes [16][64]
    u16* Pb = shQK;            // planes [32][64]  (after Qs/Ks dead)

    const int tid = threadIdx.x;
    const int lane = tid & 63, w = tid >> 6;
    const int r15 = lane & 15, quad = lane >> 4;
    const int bh = blockIdx.x;
    const int q0 = blockIdx.y << 6;
    const int wq = w * 16;

    const u16* Qg = Q + ((size_t)bh * S_ + q0) * HD_;
    const u16* Kg = K + (size_t)bh * S_ * HD_;
    const u16* Vg = V + (size_t)bh * S_ * HD_;

    // stage Q tile 64x128 -> plane-major
#pragma unroll
    for (int p = 0; p < 4; ++p) {
        int task = tid + (p << 8);
        int r = task & 63, c = task >> 6;
        *(uint4*)&Qs[(c*64 + r)*8] = *(const uint4*)&Qg[(size_t)r*HD_ + c*8];
    }

    const floatx4 fzero = {0.f, 0.f, 0.f, 0.f};
    floatx4 sc[4][4];                          // [kt][ni]; rows wq+quad*4+reg
    for (int kt = 0; kt < 4; ++kt) {
        __syncthreads();
#pragma unroll
        for (int p = 0; p < 4; ++p) {
            int task = tid + (p << 8);
            int r = task & 63, c = task >> 6;
            *(uint4*)&Ks[(c*64 + r)*8] = *(const uint4*)&Kg[(size_t)(kt*64 + r)*HD_ + c*8];
        }
        __syncthreads();
#pragma unroll
        for (int ni = 0; ni < 4; ++ni) sc[kt][ni] = fzero;
#pragma unroll
        for (int ks = 0; ks < 4; ++ks) {
            short8 a = *(const short8*)&Qs[((ks*4 + quad)*64 + wq + r15)*8];
#pragma unroll
            for (int ni = 0; ni < 4; ++ni) {
                short8 b = *(const short8*)&Ks[((ks*4 + quad)*64 + ni*16 + r15)*8];
                sc[kt][ni] = __builtin_amdgcn_mfma_f32_16x16x32_bf16(a, b, sc[kt][ni], 0, 0, 0);
            }
        }
    }
    __syncthreads();   // all Qs/Ks reads complete before Pb overwrites them

    // ---- softmax in registers (rows wq+quad*4+r; 16 col-lanes via shuffle) ----
#pragma unroll
    for (int kt = 0; kt < 4; ++kt)
#pragma unroll
        for (int ni = 0; ni < 4; ++ni) sc[kt][ni] *= SCALE;

    float rinv4[4], mrow4[4];
#pragma unroll
    for (int r = 0; r < 4; ++r) {
        float m = -1e30f;
#pragma unroll
        for (int kt = 0; kt < 4; ++kt)
#pragma unroll
            for (int ni = 0; ni < 4; ++ni) m = fmaxf(m, sc[kt][ni][r]);
#pragma unroll
        for (int o = 1; o < 16; o <<= 1) m = fmaxf(m, __shfl_xor(m, o));
        mrow4[r] = m;
    }
#pragma unroll
    for (int r = 0; r < 4; ++r) {
        float ssum = 0.f;
#pragma unroll
        for (int kt = 0; kt < 4; ++kt)
#pragma unroll
            for (int ni = 0; ni < 4; ++ni) {
                float e = __expf(sc[kt][ni][r] - mrow4[r]);
                sc[kt][ni][r] = e;
                ssum += e;
            }
#pragma unroll
        for (int o = 1; o < 16; o <<= 1) ssum += __shfl_xor(ssum, o);
        rinv4[r] = 1.f / ssum;
    }
    // write P bf16 -> Pb plane-major: elem(row,col) at chunk (col>>3)*64+row
#pragma unroll
    for (int r = 0; r < 4; ++r) {
        int row = wq + quad*4 + r;
#pragma unroll
        for (int kt = 0; kt < 4; ++kt)
#pragma unroll
            for (int ni = 0; ni < 4; ++ni) {
                int col = kt*64 + ni*16 + r15;
                Pb[((col >> 3)*64 + row)*8 + (col & 7)] = rne_bf16(sc[kt][ni][r] * rinv4[r]);
            }
    }

    // ---- O = P V ----
    floatx4 oacc[8];
#pragma unroll
    for (int di = 0; di < 8; ++di) oacc[di] = fzero;

    for (int vt = 0; vt < 4; ++vt) {
        __syncthreads();
        // stage V tile transposed: Vt planes [8][128] chunks; elem(d,s') at chunk (s'>>3)*128+d
#pragma unroll
        for (int p = 0; p < 4; ++p) {
            int task = tid + (p << 8);
            int r = task & 63, dc = task >> 6;          // s' = r, d-chunk dc
            ushort8 v = *(const ushort8*)&Vg[(size_t)(vt*64 + r)*HD_ + dc*8];
#pragma unroll
            for (int j = 0; j < 8; ++j)
                shV[(((r >> 3)*128) + dc*8 + j)*8 + (r & 7)] = v[j];
        }
        __syncthreads();
#pragma unroll
        for (int ks = 0; ks < 2; ++ks) {
            int colbase = vt*64 + ks*32 + quad*8;
            short8 a = *(const short8*)&Pb[((colbase >> 3)*64 + wq + r15)*8];
            int sp = ks*32 + quad*8;
#pragma unroll
            for (int di = 0; di < 8; ++di) {
                short8 b = *(const short8*)&shV[((sp >> 3)*128 + di*16 + r15)*8];
                oacc[di] = __builtin_amdgcn_mfma_f32_16x16x32_bf16(a, b, oacc[di], 0, 0, 0);
            }
        }
    }

    // epilogue: att[m][n] -> hi/lo split bf16, m = b*256+s, n = h*128 + d
    const int brow = bh >> 4, h = bh & 15;
#pragma unroll
    for (int r = 0; r < 4; ++r) {
        size_t base = ((size_t)(brow*S_ + q0 + wq + quad*4 + r)) * H_ + h*128 + r15;
#pragma unroll
        for (int di = 0; di < 8; ++di) {
            float x = oacc[di][r];
            u16 hb = rne_bf16(x);
            Ohi[base + di*16] = hb;
            Olo[base + di*16] = rne_bf16(x - bf16_to_f(hb));
        }
    }
}

// ---------------------------------------------------------------------------
extern "C" void kernel_launch(void* const* d_in, const int* in_sizes, int n_in,
                              void* d_out, int out_size, void* d_ws, size_t ws_size,
                              hipStream_t stream)
{
    const float* X  = (const float*)d_in[0];
    const float* Wp[4] = {(const float*)d_in[1], (const float*)d_in[2],
                          (const float*)d_in[3], (const float*)d_in[4]};   // q,k,v,o
    float* outp = (float*)d_out;

    char* ws = (char*)d_ws;
    u16* Xhi = (u16*)ws;                          //  33.5 MB
    u16* Xlo = (u16*)(ws + 33554432);             //  33.5 MB
    u16* Wsp = (u16*)(ws + 67108864);             //  8 x 8.4 MB (hi/lo per W)
    u16* Qbf = (u16*)(ws + 134217728);            //  33.5 MB [B,NH,S,HD]
    u16* Kbf = (u16*)(ws + 167772160);
    u16* Vbf = (u16*)(ws + 201326592);            //  total 235 MB
    u16* Ahi = Xhi;                               // alias: X-split dead after projections
    u16* Alo = Xlo;

    split_kernel<<<(M_*H_/4)/256, 256, 0, stream>>>(X, Xhi, Xlo, M_*H_/4);
    for (int i = 0; i < 4; ++i)
        split_kernel<<<(H_*H_/4)/256, 256, 0, stream>>>(Wp[i],
            Wsp + (size_t)(2*i)*4194304, Wsp + (size_t)(2*i+1)*4194304, H_*H_/4);

    gemm_split256<<<256, 512, 0, stream>>>(Xhi, Xlo, Wsp + 0*4194304, Wsp + 1*4194304, Qbf, 0);
    gemm_split256<<<256, 512, 0, stream>>>(Xhi, Xlo, Wsp + 2*4194304, Wsp + 3*4194304, Kbf, 0);
    gemm_split256<<<256, 512, 0, stream>>>(Xhi, Xlo, Wsp + 4*4194304, Wsp + 5*4194304, Vbf, 0);
    rope_bf<<<dim3(32768, 2), 256, 0, stream>>>(Qbf, Kbf);
    attn_mfma<<<dim3(B_*NH_, 4), 256, 0, stream>>>(Qbf, Kbf, Vbf, Ahi, Alo);
    gemm_split256<<<256, 512, 0, stream>>>(Ahi, Alo, Wsp + 6*4194304, Wsp + 7*4194304, outp, 1);
}